// Round 1
// baseline (1183.383 us; speedup 1.0000x reference)
//
#include <hip/hip_runtime.h>

// Problem: N=C=H=W=64. n = N*H*W = 262144 samples per channel.
// ws layout:
//   [0,     32768)  S      double[64*64]   Gram accumulator
//   [32768, 33280)  rowsum double[64]
//   [33280, 49664)  T      float[64*64]    folded transform
//   [49664, 49920)  off    float[64]       folded offset

__global__ __launch_bounds__(256) void zca_zero_k(double* __restrict__ p) {
  for (int i = threadIdx.x; i < 4160; i += 256) p[i] = 0.0;
}

// Gram + row sums. Grid 256: block = (n = b>>2, hw quarter = b&3). 8 tiles of 128.
__global__ __launch_bounds__(256) void zca_gram_k(const float* __restrict__ x,
                                                  double* __restrict__ S,
                                                  double* __restrict__ rowsum) {
  __shared__ float X[64][129];  // +1 word pad -> 2-way max bank aliasing (free)
  const int t = threadIdx.x;
  const int n = blockIdx.x >> 2;
  const int hw0 = (blockIdx.x & 3) << 10;
  const float* xb = x + ((size_t)n << 18);  // n*64*4096
  const int c0 = (t >> 4) << 2;
  const int d0 = (t & 15) << 2;
  double acc[4][4];
#pragma unroll
  for (int i = 0; i < 4; ++i)
#pragma unroll
    for (int j = 0; j < 4; ++j) acc[i][j] = 0.0;
  double rs[4] = {0.0, 0.0, 0.0, 0.0};

  for (int tile = 0; tile < 8; ++tile) {
    const int k0 = hw0 + (tile << 7);
#pragma unroll
    for (int r = 0; r < 8; ++r) {
      const int idx4 = t + (r << 8);
      const int c = idx4 >> 5;
      const int kk = (idx4 & 31) << 2;
      const float4 v = *reinterpret_cast<const float4*>(xb + ((size_t)c << 12) + k0 + kk);
      X[c][kk] = v.x; X[c][kk + 1] = v.y; X[c][kk + 2] = v.z; X[c][kk + 3] = v.w;
    }
    __syncthreads();
    float accf[4][4];
#pragma unroll
    for (int i = 0; i < 4; ++i)
#pragma unroll
      for (int j = 0; j < 4; ++j) accf[i][j] = 0.0f;
    float rsf[4] = {0.f, 0.f, 0.f, 0.f};
    for (int kk = 0; kk < 128; ++kk) {
      float a[4], b[4];
#pragma unroll
      for (int i = 0; i < 4; ++i) a[i] = X[c0 + i][kk];
#pragma unroll
      for (int j = 0; j < 4; ++j) b[j] = X[d0 + j][kk];
#pragma unroll
      for (int i = 0; i < 4; ++i) {
#pragma unroll
        for (int j = 0; j < 4; ++j) accf[i][j] = fmaf(a[i], b[j], accf[i][j]);
        rsf[i] += a[i];
      }
    }
#pragma unroll
    for (int i = 0; i < 4; ++i) {
#pragma unroll
      for (int j = 0; j < 4; ++j) acc[i][j] += (double)accf[i][j];
      rs[i] += (double)rsf[i];
    }
    __syncthreads();
  }
#pragma unroll
  for (int i = 0; i < 4; ++i)
#pragma unroll
    for (int j = 0; j < 4; ++j)
      atomicAdd(&S[(c0 + i) * 64 + d0 + j], acc[i][j]);
  if ((t & 15) == 0) {
#pragma unroll
    for (int i = 0; i < 4; ++i) atomicAdd(&rowsum[c0 + i], rs[i]);
  }
}

// Single block: build M0, Jacobi eigensolve (f64), build folded T/off.
__global__ __launch_bounds__(256) void zca_solve_k(const double* __restrict__ S,
                                                   const double* __restrict__ rowsum,
                                                   const float* __restrict__ weight,
                                                   const float* __restrict__ bias,
                                                   float* __restrict__ T,
                                                   float* __restrict__ offv) {
  __shared__ double A[64][65];   // padded: row & col access both 2-way max
  __shared__ double VT[64][64];  // eigenvectors, transposed (row k = eigvec k)
  __shared__ double mu[64], sig[64];
  __shared__ double cs[32], sn[32];
  __shared__ double evals[64];
  __shared__ int idxs[64];
  __shared__ double wk[64];
  __shared__ double red[4];
  __shared__ double offmax_sh;
  const int t = threadIdx.x;
  const double n = 262144.0;

  if (t < 64) {
    const double m = rowsum[t] / n;
    const double var = (S[t * 64 + t] - n * m * m) / (n - 1.0);
    mu[t] = m;
    sig[t] = sqrt(var + 1e-5);
  }
  __syncthreads();
  for (int e = t; e < 4096; e += 256) {
    const int i = e >> 6, j = e & 63;
    double v = (S[e] - n * mu[i] * mu[j]) / (n * sig[i] * sig[j]);
    if (i == j) v += 1e-5;
    A[i][j] = v;
    VT[i][j] = (i == j) ? 1.0 : 0.0;
  }
  __syncthreads();

  // Parallel cyclic Jacobi: round-robin pairing, 32 disjoint pairs/round.
  for (int sweep = 0; sweep < 24; ++sweep) {
    for (int round = 0; round < 63; ++round) {
      if (t < 32) {
        const int p = (t == 0) ? 0 : 1 + (t - 1 + round) % 63;
        const int q = 1 + (62 - t + round) % 63;
        const double app = A[p][p], aqq = A[q][q], apq = A[p][q];
        double c = 1.0, s = 0.0;
        if (apq != 0.0) {
          const double tau = (aqq - app) / (2.0 * apq);
          const double tt = (tau >= 0.0 ? 1.0 : -1.0) / (fabs(tau) + sqrt(1.0 + tau * tau));
          c = 1.0 / sqrt(1.0 + tt * tt);
          s = tt * c;
        }
        cs[t] = c; sn[t] = s;
      }
      __syncthreads();
      // Row phase: A <- J^T A   (32 pairs x 64 cols = 2048 updates)
#pragma unroll
      for (int r = 0; r < 8; ++r) {
        const int u = t + (r << 8);
        const int j = u >> 6;
        const int i = u & 63;
        const int p = (j == 0) ? 0 : 1 + (j - 1 + round) % 63;
        const int q = 1 + (62 - j + round) % 63;
        const double c = cs[j], s = sn[j];
        const double ap = A[p][i], aq = A[q][i];
        A[p][i] = c * ap - s * aq;
        A[q][i] = s * ap + c * aq;
      }
      __syncthreads();
      // Col phase: A <- A J ; V <- V J (as rows of VT)
#pragma unroll
      for (int r = 0; r < 8; ++r) {
        const int u = t + (r << 8);
        const int j = u >> 6;
        const int i = u & 63;
        const int p = (j == 0) ? 0 : 1 + (j - 1 + round) % 63;
        const int q = 1 + (62 - j + round) % 63;
        const double c = cs[j], s = sn[j];
        const double ap = A[i][p], aq = A[i][q];
        A[i][p] = c * ap - s * aq;
        A[i][q] = s * ap + c * aq;
        const double vp = VT[p][i], vq = VT[q][i];
        VT[p][i] = c * vp - s * vq;
        VT[q][i] = s * vp + c * vq;
      }
      __syncthreads();
    }
    // convergence: max |off-diagonal|
    double mx = 0.0;
    for (int e = t; e < 4096; e += 256) {
      const int i = e >> 6, j = e & 63;
      if (i != j) mx = fmax(mx, fabs(A[i][j]));
    }
#pragma unroll
    for (int o = 32; o > 0; o >>= 1) mx = fmax(mx, __shfl_down(mx, o));
    if ((t & 63) == 0) red[t >> 6] = mx;
    __syncthreads();
    if (t == 0) offmax_sh = fmax(fmax(red[0], red[1]), fmax(red[2], red[3]));
    __syncthreads();
    if (offmax_sh < 1e-11) break;  // uniform
  }
  __syncthreads();

  if (t < 64) evals[t] = A[t][t];
  __syncthreads();
  // descending rank sort (ties broken by index -> unique ranks)
  if (t < 64) {
    const double e = evals[t];
    int rank = 0;
    for (int j = 0; j < 64; ++j) {
      const double ej = evals[j];
      if (ej > e || (ej == e && j < t)) ++rank;
    }
    idxs[rank] = t;
  }
  __syncthreads();
  // energy threshold / active logic (faithful to reference scan semantics)
  if (t == 0) {
    double total = 0.0;
    for (int j = 0; j < 64; ++j) total += evals[idxs[j]];
    double cum = 0.0;
    bool done = false;
    for (int k = 0; k < 64; ++k) {
      const double ek = evals[idxs[k]];
      cum += ek;
      double w = 0.0;
      if (k < 32 && !done) w = 1.0 / sqrt(ek);  // active before done-update
      if (cum / total >= 0.95) done = true;
      wk[k] = w;
    }
  }
  __syncthreads();
  // Wxr into A (A is spent): Wxr[i][j] = sum_k wk[k] * v_k[i] * v_k[j]
  for (int e = t; e < 4096; e += 256) {
    const int i = e >> 6, j = e & 63;
    double sum = 0.0;
#pragma unroll 8
    for (int k = 0; k < 32; ++k) {
      const int sk = idxs[k];
      sum += wk[k] * VT[sk][i] * VT[sk][j];
    }
    A[i][j] = sum;
  }
  __syncthreads();
  // Fold: T[c][d] = weight[c]*Wxr[c][d]/sig[d]; off[c] = bias[c] - sum_d T*mu[d]
  for (int e = t; e < 4096; e += 256) {
    const int c = e >> 6, d = e & 63;
    T[e] = (float)((double)weight[c] * A[c][d] / sig[d]);
  }
  if (t < 64) {
    double o = (double)bias[t];
    const double wc = (double)weight[t];
    for (int d = 0; d < 64; ++d) o -= wc * A[t][d] / sig[d] * mu[d];
    offv[t] = (float)o;
  }
}

// out[n,c,k] = sum_d T[c][d]*x[n,d,k] + off[c].  Grid 1024: (n = b>>4, 256 k/block)
__global__ __launch_bounds__(256) void zca_apply_k(const float* __restrict__ x,
                                                   const float* __restrict__ T,
                                                   const float* __restrict__ offv,
                                                   float* __restrict__ out) {
  __shared__ float Tl[64][64];
  __shared__ float offl[64];
  const int t = threadIdx.x;
  for (int e = t; e < 4096; e += 256) Tl[e >> 6][e & 63] = T[e];
  if (t < 64) offl[t] = offv[t];
  __syncthreads();
  const int n = blockIdx.x >> 4;
  const int k = ((blockIdx.x & 15) << 8) + t;
  const float* xb = x + ((size_t)n << 18) + k;
  float acc[64];
#pragma unroll
  for (int c = 0; c < 64; ++c) acc[c] = offl[c];
  float xv = xb[0];
  for (int d = 0; d < 64; ++d) {
    const float xn = (d < 63) ? xb[(size_t)(d + 1) << 12] : 0.f;  // prefetch
#pragma unroll
    for (int c = 0; c < 64; ++c) acc[c] = fmaf(Tl[c][d], xv, acc[c]);
    xv = xn;
  }
  float* ob = out + ((size_t)n << 18) + k;
#pragma unroll
  for (int c = 0; c < 64; ++c) ob[(size_t)c << 12] = acc[c];
}

extern "C" void kernel_launch(void* const* d_in, const int* in_sizes, int n_in,
                              void* d_out, int out_size, void* d_ws, size_t ws_size,
                              hipStream_t stream) {
  const float* x = (const float*)d_in[0];
  const float* weight = (const float*)d_in[1];
  const float* bias = (const float*)d_in[2];
  float* out = (float*)d_out;
  char* ws = (char*)d_ws;
  double* S = (double*)ws;
  double* rowsum = (double*)(ws + 32768);
  float* T = (float*)(ws + 33280);
  float* offv = (float*)(ws + 49664);

  hipLaunchKernelGGL(zca_zero_k, dim3(1), dim3(256), 0, stream, S);
  hipLaunchKernelGGL(zca_gram_k, dim3(256), dim3(256), 0, stream, x, S, rowsum);
  hipLaunchKernelGGL(zca_solve_k, dim3(1), dim3(256), 0, stream, S, rowsum, weight, bias, T, offv);
  hipLaunchKernelGGL(zca_apply_k, dim3(1024), dim3(256), 0, stream, x, T, offv, out);
}

// Round 2
// 766.462 us; speedup vs baseline: 1.5440x; 1.5440x over previous
//
#include <hip/hip_runtime.h>

// Problem: N=C=H=W=64. n = N*H*W = 262144 samples per channel.
// ws layout:
//   [0,     32768)  S      double[64*64]   Gram accumulator
//   [32768, 33280)  rowsum double[64]
//   [33280, 49664)  T      float[64*64]    folded transform
//   [49664, 49920)  off    float[64]       folded offset

__global__ __launch_bounds__(256) void zca_zero_k(double* __restrict__ p) {
  for (int i = threadIdx.x; i < 4160; i += 256) p[i] = 0.0;
}

// Gram + row sums. Grid 256: block = (n = b>>2, hw quarter = b&3). 8 tiles of 128.
__global__ __launch_bounds__(256) void zca_gram_k(const float* __restrict__ x,
                                                  double* __restrict__ S,
                                                  double* __restrict__ rowsum) {
  __shared__ float X[64][129];
  const int t = threadIdx.x;
  const int n = blockIdx.x >> 2;
  const int hw0 = (blockIdx.x & 3) << 10;
  const float* xb = x + ((size_t)n << 18);
  const int c0 = (t >> 4) << 2;
  const int d0 = (t & 15) << 2;
  double acc[4][4];
#pragma unroll
  for (int i = 0; i < 4; ++i)
#pragma unroll
    for (int j = 0; j < 4; ++j) acc[i][j] = 0.0;
  double rs[4] = {0.0, 0.0, 0.0, 0.0};

  for (int tile = 0; tile < 8; ++tile) {
    const int k0 = hw0 + (tile << 7);
#pragma unroll
    for (int r = 0; r < 8; ++r) {
      const int idx4 = t + (r << 8);
      const int c = idx4 >> 5;
      const int kk = (idx4 & 31) << 2;
      const float4 v = *reinterpret_cast<const float4*>(xb + ((size_t)c << 12) + k0 + kk);
      X[c][kk] = v.x; X[c][kk + 1] = v.y; X[c][kk + 2] = v.z; X[c][kk + 3] = v.w;
    }
    __syncthreads();
    float accf[4][4];
#pragma unroll
    for (int i = 0; i < 4; ++i)
#pragma unroll
      for (int j = 0; j < 4; ++j) accf[i][j] = 0.0f;
    float rsf[4] = {0.f, 0.f, 0.f, 0.f};
    for (int kk = 0; kk < 128; ++kk) {
      float a[4], b[4];
#pragma unroll
      for (int i = 0; i < 4; ++i) a[i] = X[c0 + i][kk];
#pragma unroll
      for (int j = 0; j < 4; ++j) b[j] = X[d0 + j][kk];
#pragma unroll
      for (int i = 0; i < 4; ++i) {
#pragma unroll
        for (int j = 0; j < 4; ++j) accf[i][j] = fmaf(a[i], b[j], accf[i][j]);
        rsf[i] += a[i];
      }
    }
#pragma unroll
    for (int i = 0; i < 4; ++i) {
#pragma unroll
      for (int j = 0; j < 4; ++j) acc[i][j] += (double)accf[i][j];
      rs[i] += (double)rsf[i];
    }
    __syncthreads();
  }
#pragma unroll
  for (int i = 0; i < 4; ++i)
#pragma unroll
    for (int j = 0; j < 4; ++j)
      atomicAdd(&S[(c0 + i) * 64 + d0 + j], acc[i][j]);
  if ((t & 15) == 0) {
#pragma unroll
    for (int i = 0; i < 4; ++i) atomicAdd(&rowsum[c0 + i], rs[i]);
  }
}

// round-robin tournament pairing: 32 disjoint pairs covering all 64 indices,
// over 63 rounds every unordered pair appears exactly once.
__device__ __forceinline__ void zca_sched(int j, int r, int& p, int& q) {
  if (j == 0) {
    p = 0;
    int a = 62 + r; if (a >= 63) a -= 63;
    q = 1 + a;
  } else {
    int a = j - 1 + r;  if (a >= 63) a -= 63;
    int b = 62 - j + r; if (b >= 63) b -= 63;
    p = 1 + a;
    q = 1 + b;
  }
}

// Single block: build E = M0 - I (f32), parallel Jacobi in f32 with rotation
// skipping, then fold into T/off (f64 where free).
// f32 is sufficient: working on E (entries ~1e-3..0.04) gives absolute errors
// ~1e-7; eigenvalue gaps ~5e-4 (ordering safe) and cut-subspace angle error
// ~1e-7/5e-4 = 2e-4 -> out error ~1e-3 << 0.066 threshold.
__global__ __launch_bounds__(256) void zca_solve_k(const double* __restrict__ S,
                                                   const double* __restrict__ rowsum,
                                                   const float* __restrict__ weight,
                                                   const float* __restrict__ bias,
                                                   float* __restrict__ T,
                                                   float* __restrict__ offv) {
  __shared__ __align__(16) float A[64 * 66];   // stride 66: float2-aligned rows
  __shared__ __align__(16) float VT[64 * 64];  // row k = eigenvector k
  __shared__ double mu[64], sig[64];
  __shared__ float cs[32], sn[32];
  __shared__ double evals[64];
  __shared__ double wk[64];
  __shared__ int idxs[64];
  __shared__ int any_rot;
  const int t = threadIdx.x;
  const double n = 262144.0;

  if (t < 64) {
    const double m = rowsum[t] / n;
    const double var = (S[t * 64 + t] - n * m * m) / (n - 1.0);
    mu[t] = m;
    sig[t] = sqrt(var + 1e-5);
  }
  __syncthreads();
  // E = M0 - I  (M0 = corr + 1e-5*I)
  for (int e = t; e < 4096; e += 256) {
    const int i = e >> 6, j = e & 63;
    double v = (S[e] - n * mu[i] * mu[j]) / (n * sig[i] * sig[j]);
    if (i == j) v += 1e-5 - 1.0;
    A[i * 66 + j] = (float)v;
    VT[i * 64 + j] = (i == j) ? 1.0f : 0.0f;
  }
  __syncthreads();

  // ---- f32 parallel Jacobi: 2 barriers/round, skip tiny rotations ----
  const int g = t >> 3, lane = t & 7;      // phase-1: 32 groups x 8 threads
  const int j2 = t & 31, ib = t >> 5;      // phase-2: 32 pairs x 8 row-blocks
  for (int sweep = 0; sweep < 10; ++sweep) {
    if (t == 0) any_rot = 0;
    __syncthreads();
    for (int round = 0; round < 63; ++round) {
      // phase 1: angle + row-rotation of A rows p,q + VT rows p,q (group-local)
      int p, q;
      zca_sched(g, round, p, q);
      const float app = A[p * 66 + p], aqq = A[q * 66 + q], apq = A[p * 66 + q];
      if (fabsf(apq) > 1e-7f) {
        const float tau = (aqq - app) / (2.0f * apq);
        const float tt = (tau >= 0.0f ? 1.0f : -1.0f) / (fabsf(tau) + sqrtf(1.0f + tau * tau));
        const float c = 1.0f / sqrtf(1.0f + tt * tt);
        const float s = tt * c;
        if (lane == 0) { cs[g] = c; sn[g] = s; any_rot = 1; }
        float* rp = &A[p * 66];
        float* rq = &A[q * 66];
#pragma unroll
        for (int it = 0; it < 4; ++it) {
          const int m2 = (lane + (it << 3)) << 1;
          const float2 ap = *reinterpret_cast<float2*>(rp + m2);
          const float2 aq = *reinterpret_cast<float2*>(rq + m2);
          float2 np, nq;
          np.x = c * ap.x - s * aq.x; np.y = c * ap.y - s * aq.y;
          nq.x = s * ap.x + c * aq.x; nq.y = s * ap.y + c * aq.y;
          *reinterpret_cast<float2*>(rp + m2) = np;
          *reinterpret_cast<float2*>(rq + m2) = nq;
        }
        float* vp = &VT[p * 64];
        float* vq = &VT[q * 64];
#pragma unroll
        for (int it = 0; it < 4; ++it) {
          const int m2 = (lane + (it << 3)) << 1;
          const float2 ap = *reinterpret_cast<float2*>(vp + m2);
          const float2 aq = *reinterpret_cast<float2*>(vq + m2);
          float2 np, nq;
          np.x = c * ap.x - s * aq.x; np.y = c * ap.y - s * aq.y;
          nq.x = s * ap.x + c * aq.x; nq.y = s * ap.y + c * aq.y;
          *reinterpret_cast<float2*>(vp + m2) = np;
          *reinterpret_cast<float2*>(vq + m2) = nq;
        }
      } else if (lane == 0) {
        cs[g] = 1.0f; sn[g] = 0.0f;
      }
      __syncthreads();
      // phase 2: column rotation of A (element-disjoint across pairs)
      const float c2 = cs[j2], s2 = sn[j2];
      if (s2 != 0.0f) {
        int p2, q2;
        zca_sched(j2, round, p2, q2);
#pragma unroll
        for (int it = 0; it < 8; ++it) {
          const int i = ib + (it << 3);
          const float ap = A[i * 66 + p2], aq = A[i * 66 + q2];
          A[i * 66 + p2] = c2 * ap - s2 * aq;
          A[i * 66 + q2] = s2 * ap + c2 * aq;
        }
      }
      __syncthreads();
    }
    const int go = any_rot;
    __syncthreads();  // protect read from next sweep's reset
    if (!go) break;
  }

  if (t < 64) evals[t] = (double)A[t * 66 + t];  // eigenvalue = 1 + evals[t]
  __syncthreads();
  // descending rank sort (ties broken by index -> unique ranks)
  if (t < 64) {
    const double e = evals[t];
    int rank = 0;
    for (int j = 0; j < 64; ++j) {
      const double ej = evals[j];
      if (ej > e || (ej == e && j < t)) ++rank;
    }
    idxs[rank] = t;
  }
  __syncthreads();
  // energy threshold / active logic (faithful to reference scan semantics)
  if (t == 0) {
    double total = 0.0;
    for (int j = 0; j < 64; ++j) total += 1.0 + evals[j];
    double cum = 0.0;
    bool done = false;
    for (int k = 0; k < 64; ++k) {
      const double lam = 1.0 + evals[idxs[k]];
      cum += lam;
      double w = 0.0;
      if (k < 32 && !done) w = 1.0 / sqrt(lam);
      if (cum / total >= 0.95) done = true;
      wk[k] = w;
    }
  }
  __syncthreads();
  // Wxr[c][d] = sum_k wk[k] v_k[c] v_k[d]; write T, stash Wxr rows into A.
  {
    const int c = t >> 2, db = (t & 3) << 4;
    double acc[16];
#pragma unroll
    for (int d = 0; d < 16; ++d) acc[d] = 0.0;
    for (int k = 0; k < 32; ++k) {
      const int sk = idxs[k];
      const double vc = wk[k] * (double)VT[sk * 64 + c];
#pragma unroll
      for (int d = 0; d < 16; ++d) acc[d] += vc * (double)VT[sk * 64 + db + d];
    }
    const double wc = (double)weight[c];
#pragma unroll
    for (int d = 0; d < 16; ++d) {
      A[c * 66 + db + d] = (float)acc[d];
      T[c * 64 + db + d] = (float)(wc * acc[d] / sig[db + d]);
    }
  }
  __syncthreads();
  if (t < 64) {
    double o = (double)bias[t];
    const double wc = (double)weight[t];
    for (int d = 0; d < 64; ++d) o -= wc * (double)A[t * 66 + d] / sig[d] * mu[d];
    offv[t] = (float)o;
  }
}

// out[n,c,k] = sum_d T[c][d]*x[n,d,k] + off[c].  Grid 1024: (n = b>>4, 256 k/block)
__global__ __launch_bounds__(256) void zca_apply_k(const float* __restrict__ x,
                                                   const float* __restrict__ T,
                                                   const float* __restrict__ offv,
                                                   float* __restrict__ out) {
  __shared__ float Tl[64][64];
  __shared__ float offl[64];
  const int t = threadIdx.x;
  for (int e = t; e < 4096; e += 256) Tl[e >> 6][e & 63] = T[e];
  if (t < 64) offl[t] = offv[t];
  __syncthreads();
  const int n = blockIdx.x >> 4;
  const int k = ((blockIdx.x & 15) << 8) + t;
  const float* xb = x + ((size_t)n << 18) + k;
  float acc[64];
#pragma unroll
  for (int c = 0; c < 64; ++c) acc[c] = offl[c];
  float xv = xb[0];
  for (int d = 0; d < 64; ++d) {
    const float xn = (d < 63) ? xb[(size_t)(d + 1) << 12] : 0.f;
#pragma unroll
    for (int c = 0; c < 64; ++c) acc[c] = fmaf(Tl[c][d], xv, acc[c]);
    xv = xn;
  }
  float* ob = out + ((size_t)n << 18) + k;
#pragma unroll
  for (int c = 0; c < 64; ++c) ob[(size_t)c << 12] = acc[c];
}

extern "C" void kernel_launch(void* const* d_in, const int* in_sizes, int n_in,
                              void* d_out, int out_size, void* d_ws, size_t ws_size,
                              hipStream_t stream) {
  const float* x = (const float*)d_in[0];
  const float* weight = (const float*)d_in[1];
  const float* bias = (const float*)d_in[2];
  float* out = (float*)d_out;
  char* ws = (char*)d_ws;
  double* S = (double*)ws;
  double* rowsum = (double*)(ws + 32768);
  float* T = (float*)(ws + 33280);
  float* offv = (float*)(ws + 49664);

  hipLaunchKernelGGL(zca_zero_k, dim3(1), dim3(256), 0, stream, S);
  hipLaunchKernelGGL(zca_gram_k, dim3(256), dim3(256), 0, stream, x, S, rowsum);
  hipLaunchKernelGGL(zca_solve_k, dim3(1), dim3(256), 0, stream, S, rowsum, weight, bias, T, offv);
  hipLaunchKernelGGL(zca_apply_k, dim3(1024), dim3(256), 0, stream, x, T, offv, out);
}

// Round 3
// 623.507 us; speedup vs baseline: 1.8979x; 1.2293x over previous
//
#include <hip/hip_runtime.h>

// Problem: N=C=H=W=64. n = N*H*W = 262144 samples per channel.
// ws layout:
//   [0,     32768)  S      double[64*64]   Gram accumulator
//   [32768, 33280)  rowsum double[64]
//   [33280, 49664)  T      float[64*64]    folded transform
//   [49664, 49920)  off    float[64]       folded offset

__global__ __launch_bounds__(256) void zca_zero_k(double* __restrict__ p) {
  for (int i = threadIdx.x; i < 4160; i += 256) p[i] = 0.0;
}

// Gram + row sums. Grid 512: (n = b>>3, hw eighth = b&7). 4 tiles of 128.
// Tile staged TRANSPOSED: XT[kk][c] so both operand fragments are b128 reads.
__global__ __launch_bounds__(256) void zca_gram_k(const float* __restrict__ x,
                                                  double* __restrict__ S,
                                                  double* __restrict__ rowsum) {
  __shared__ float XT[128 * 72];  // row kk (stride 72), 64 channels
  const int t = threadIdx.x;
  const int n = blockIdx.x >> 3;
  const int k0base = (blockIdx.x & 7) << 9;
  const float* xb = x + ((size_t)n << 18);
  const int cg = t >> 4, dg = t & 15;   // 4x4 output block (rows 4cg.., cols 4dg..)
  const int sc = t & 63, kq = t >> 6;   // staging: channel, k-quarter

  double acc[4][4];
#pragma unroll
  for (int i = 0; i < 4; ++i)
#pragma unroll
    for (int j = 0; j < 4; ++j) acc[i][j] = 0.0;
  double rs[4] = {0.0, 0.0, 0.0, 0.0};

  for (int tile = 0; tile < 4; ++tile) {
    const int k0 = k0base + (tile << 7);
#pragma unroll
    for (int r = 0; r < 8; ++r) {
      const int kk = ((kq << 3) + r) << 2;
      const float4 v = *reinterpret_cast<const float4*>(xb + ((size_t)sc << 12) + k0 + kk);
      XT[(kk + 0) * 72 + sc] = v.x;
      XT[(kk + 1) * 72 + sc] = v.y;
      XT[(kk + 2) * 72 + sc] = v.z;
      XT[(kk + 3) * 72 + sc] = v.w;
    }
    __syncthreads();
    float accf[4][4];
#pragma unroll
    for (int i = 0; i < 4; ++i)
#pragma unroll
      for (int j = 0; j < 4; ++j) accf[i][j] = 0.0f;
    float rsf[4] = {0.f, 0.f, 0.f, 0.f};
#pragma unroll 2
    for (int kk = 0; kk < 128; ++kk) {
      const float4 a4 = *reinterpret_cast<const float4*>(XT + kk * 72 + (cg << 2));
      const float4 b4 = *reinterpret_cast<const float4*>(XT + kk * 72 + (dg << 2));
      const float a[4] = {a4.x, a4.y, a4.z, a4.w};
      const float b[4] = {b4.x, b4.y, b4.z, b4.w};
#pragma unroll
      for (int i = 0; i < 4; ++i) {
#pragma unroll
        for (int j = 0; j < 4; ++j) accf[i][j] = fmaf(a[i], b[j], accf[i][j]);
        rsf[i] += a[i];
      }
    }
#pragma unroll
    for (int i = 0; i < 4; ++i) {
#pragma unroll
      for (int j = 0; j < 4; ++j) acc[i][j] += (double)accf[i][j];
      rs[i] += (double)rsf[i];
    }
    __syncthreads();
  }
  const int c0 = cg << 2, d0 = dg << 2;
#pragma unroll
  for (int i = 0; i < 4; ++i)
#pragma unroll
    for (int j = 0; j < 4; ++j)
      atomicAdd(&S[(c0 + i) * 64 + d0 + j], acc[i][j]);
  if (dg == 0) {
#pragma unroll
    for (int i = 0; i < 4; ++i) atomicAdd(&rowsum[c0 + i], rs[i]);
  }
}

// round-robin tournament pairing: 32 disjoint pairs covering all 64 indices.
__device__ __forceinline__ void zca_sched(int j, int r, int& p, int& q) {
  if (j == 0) {
    p = 0;
    int a = 62 + r; if (a >= 63) a -= 63;
    q = 1 + a;
  } else {
    int a = j - 1 + r;  if (a >= 63) a -= 63;
    int b = 62 - j + r; if (b >= 63) b -= 63;
    p = 1 + a;
    q = 1 + b;
  }
}

__device__ __forceinline__ float zca_dot8(const float4& a0, const float4& a1,
                                          const float4& b0, const float4& b1) {
  float s = a0.x * b0.x;
  s = fmaf(a0.y, b0.y, s); s = fmaf(a0.z, b0.z, s); s = fmaf(a0.w, b0.w, s);
  s = fmaf(a1.x, b1.x, s); s = fmaf(a1.y, b1.y, s); s = fmaf(a1.z, b1.z, s);
  s = fmaf(a1.w, b1.w, s);
  return s;
}

// Single block: one-sided (Hestenes) Jacobi on columns of G = M0, f32.
// V accumulates rotations -> eigenvectors (exactly orthonormal columns).
// lambda_i = ||G_final[:,i]||. One barrier per round; dots reduced via shfl.
__global__ __launch_bounds__(256) void zca_solve_k(const double* __restrict__ S,
                                                   const double* __restrict__ rowsum,
                                                   const float* __restrict__ weight,
                                                   const float* __restrict__ bias,
                                                   float* __restrict__ T,
                                                   float* __restrict__ offv) {
  __shared__ __align__(16) float G[64 * 68];  // column-major, col stride 68
  __shared__ __align__(16) float V[64 * 68];
  __shared__ double mu[64], sig[64];
  __shared__ float lam[64];
  __shared__ double wk[64];
  __shared__ int idxs[64];
  __shared__ int any_rot;
  const int t = threadIdx.x;
  const double n = 262144.0;

  if (t < 64) {
    const double m = rowsum[t] / n;
    const double var = (S[t * 64 + t] - n * m * m) / (n - 1.0);
    mu[t] = m;
    sig[t] = sqrt(var + 1e-5);
  }
  __syncthreads();
  for (int e = t; e < 4096; e += 256) {
    const int col = e >> 6, row = e & 63;
    double v = (S[row * 64 + col] - n * mu[row] * mu[col]) / (n * sig[row] * sig[col]);
    if (row == col) v += 1e-5;
    G[col * 68 + row] = (float)v;
    V[col * 68 + row] = (row == col) ? 1.0f : 0.0f;
  }
  __syncthreads();

  const int g = t >> 3, lane = t & 7;
  const int o = lane << 3;  // 8 elements per lane per column
  for (int sweep = 0; sweep < 8; ++sweep) {
    if (t == 0) any_rot = 0;
    __syncthreads();
    for (int round = 0; round < 63; ++round) {
      int p, q;
      zca_sched(g, round, p, q);
      float* Gp = G + p * 68;
      float* Gq = G + q * 68;
      float4 p0 = *reinterpret_cast<float4*>(Gp + o);
      float4 p1 = *reinterpret_cast<float4*>(Gp + o + 4);
      float4 q0 = *reinterpret_cast<float4*>(Gq + o);
      float4 q1 = *reinterpret_cast<float4*>(Gq + o + 4);
      float app = zca_dot8(p0, p1, p0, p1);
      float aqq = zca_dot8(q0, q1, q0, q1);
      float apq = zca_dot8(p0, p1, q0, q1);
#pragma unroll
      for (int m = 1; m <= 4; m <<= 1) {
        app += __shfl_xor(app, m);
        aqq += __shfl_xor(aqq, m);
        apq += __shfl_xor(apq, m);
      }
      if (fabsf(apq) > 1e-8f) {
        if (lane == 0) any_rot = 1;
        const float tau = (aqq - app) / (2.0f * apq);
        const float tt = (tau >= 0.0f ? 1.0f : -1.0f) / (fabsf(tau) + sqrtf(1.0f + tau * tau));
        const float c = 1.0f / sqrtf(1.0f + tt * tt);
        const float s = tt * c;
        float4 np0, np1, nq0, nq1;
        np0.x = c * p0.x - s * q0.x; np0.y = c * p0.y - s * q0.y;
        np0.z = c * p0.z - s * q0.z; np0.w = c * p0.w - s * q0.w;
        np1.x = c * p1.x - s * q1.x; np1.y = c * p1.y - s * q1.y;
        np1.z = c * p1.z - s * q1.z; np1.w = c * p1.w - s * q1.w;
        nq0.x = s * p0.x + c * q0.x; nq0.y = s * p0.y + c * q0.y;
        nq0.z = s * p0.z + c * q0.z; nq0.w = s * p0.w + c * q0.w;
        nq1.x = s * p1.x + c * q1.x; nq1.y = s * p1.y + c * q1.y;
        nq1.z = s * p1.z + c * q1.z; nq1.w = s * p1.w + c * q1.w;
        *reinterpret_cast<float4*>(Gp + o) = np0;
        *reinterpret_cast<float4*>(Gp + o + 4) = np1;
        *reinterpret_cast<float4*>(Gq + o) = nq0;
        *reinterpret_cast<float4*>(Gq + o + 4) = nq1;
        float* Vp = V + p * 68;
        float* Vq = V + q * 68;
        float4 vp0 = *reinterpret_cast<float4*>(Vp + o);
        float4 vp1 = *reinterpret_cast<float4*>(Vp + o + 4);
        float4 vq0 = *reinterpret_cast<float4*>(Vq + o);
        float4 vq1 = *reinterpret_cast<float4*>(Vq + o + 4);
        float4 wp0, wp1, wq0, wq1;
        wp0.x = c * vp0.x - s * vq0.x; wp0.y = c * vp0.y - s * vq0.y;
        wp0.z = c * vp0.z - s * vq0.z; wp0.w = c * vp0.w - s * vq0.w;
        wp1.x = c * vp1.x - s * vq1.x; wp1.y = c * vp1.y - s * vq1.y;
        wp1.z = c * vp1.z - s * vq1.z; wp1.w = c * vp1.w - s * vq1.w;
        wq0.x = s * vp0.x + c * vq0.x; wq0.y = s * vp0.y + c * vq0.y;
        wq0.z = s * vp0.z + c * vq0.z; wq0.w = s * vp0.w + c * vq0.w;
        wq1.x = s * vp1.x + c * vq1.x; wq1.y = s * vp1.y + c * vq1.y;
        wq1.z = s * vp1.z + c * vq1.z; wq1.w = s * vp1.w + c * vq1.w;
        *reinterpret_cast<float4*>(Vp + o) = wp0;
        *reinterpret_cast<float4*>(Vp + o + 4) = wp1;
        *reinterpret_cast<float4*>(Vq + o) = wq0;
        *reinterpret_cast<float4*>(Vq + o + 4) = wq1;
      }
      __syncthreads();
    }
    const int go = any_rot;
    __syncthreads();
    if (!go) break;
  }

  // eigenvalues = column norms of converged G
  if (t < 64) {
    float s = 0.0f;
#pragma unroll
    for (int j4 = 0; j4 < 16; ++j4) {
      const float4 v = *reinterpret_cast<const float4*>(G + t * 68 + (j4 << 2));
      s = fmaf(v.x, v.x, s); s = fmaf(v.y, v.y, s);
      s = fmaf(v.z, v.z, s); s = fmaf(v.w, v.w, s);
    }
    lam[t] = sqrtf(s);
  }
  __syncthreads();
  if (t < 64) {
    const float e = lam[t];
    int rank = 0;
    for (int j = 0; j < 64; ++j) {
      const float ej = lam[j];
      if (ej > e || (ej == e && j < t)) ++rank;
    }
    idxs[rank] = t;
  }
  __syncthreads();
  if (t == 0) {
    double total = 0.0;
    for (int j = 0; j < 64; ++j) total += (double)lam[j];
    double cum = 0.0;
    bool done = false;
    for (int k = 0; k < 64; ++k) {
      const double l = (double)lam[idxs[k]];
      cum += l;
      double w = 0.0;
      if (k < 32 && !done) w = 1.0 / sqrt(l);
      if (cum / total >= 0.95) done = true;
      wk[k] = w;
    }
  }
  __syncthreads();
  // Wxr[c][d] = sum_k wk[k] v_k[c] v_k[d]; v_k = column idxs[k] of V.
  {
    const int c = t >> 2, db = (t & 3) << 4;
    double acc[16];
#pragma unroll
    for (int d = 0; d < 16; ++d) acc[d] = 0.0;
    for (int k = 0; k < 32; ++k) {
      const int sk = idxs[k];
      const double vc = wk[k] * (double)V[sk * 68 + c];
#pragma unroll
      for (int d = 0; d < 16; ++d) acc[d] += vc * (double)V[sk * 68 + db + d];
    }
    const double wc = (double)weight[c];
#pragma unroll
    for (int d = 0; d < 16; ++d) {
      G[c * 68 + db + d] = (float)acc[d];  // stash Wxr row c (G is spent)
      T[c * 64 + db + d] = (float)(wc * acc[d] / sig[db + d]);
    }
  }
  __syncthreads();
  if (t < 64) {
    double ov = (double)bias[t];
    const double wc = (double)weight[t];
    for (int d = 0; d < 64; ++d) ov -= wc * (double)G[t * 68 + d] / sig[d] * mu[d];
    offv[t] = (float)ov;
  }
}

// out[n,c,k] = sum_d T[c][d]*x[n,d,k] + off[c].
// Grid 512: (n = b>>3, 512 k per block, 2 positions per thread).
__global__ __launch_bounds__(256) void zca_apply_k(const float* __restrict__ x,
                                                   const float* __restrict__ T,
                                                   const float* __restrict__ offv,
                                                   float* __restrict__ out) {
  __shared__ __align__(16) float4 Tl4[64 * 16];  // Tl4[c*16 + d4]
  __shared__ float offl[64];
  const int t = threadIdx.x;
  for (int e = t; e < 1024; e += 256) Tl4[e] = reinterpret_cast<const float4*>(T)[e];
  if (t < 64) offl[t] = offv[t];
  __syncthreads();
  const int n = blockIdx.x >> 3;
  const int k0 = ((blockIdx.x & 7) << 9) + (t << 1);
  const float* xb = x + ((size_t)n << 18) + k0;
  float2 acc[64];
#pragma unroll
  for (int c = 0; c < 64; ++c) { acc[c].x = offl[c]; acc[c].y = offl[c]; }
  float2 xv[4];
#pragma unroll
  for (int dd = 0; dd < 4; ++dd)
    xv[dd] = *reinterpret_cast<const float2*>(xb + ((size_t)dd << 12));
  for (int d4 = 0; d4 < 16; ++d4) {
    float2 xn[4];
    if (d4 < 15) {
#pragma unroll
      for (int dd = 0; dd < 4; ++dd)
        xn[dd] = *reinterpret_cast<const float2*>(xb + ((size_t)((d4 + 1) * 4 + dd) << 12));
    }
#pragma unroll
    for (int c = 0; c < 64; ++c) {
      const float4 tv = Tl4[(c << 4) + d4];
      acc[c].x = fmaf(tv.x, xv[0].x, acc[c].x); acc[c].y = fmaf(tv.x, xv[0].y, acc[c].y);
      acc[c].x = fmaf(tv.y, xv[1].x, acc[c].x); acc[c].y = fmaf(tv.y, xv[1].y, acc[c].y);
      acc[c].x = fmaf(tv.z, xv[2].x, acc[c].x); acc[c].y = fmaf(tv.z, xv[2].y, acc[c].y);
      acc[c].x = fmaf(tv.w, xv[3].x, acc[c].x); acc[c].y = fmaf(tv.w, xv[3].y, acc[c].y);
    }
#pragma unroll
    for (int dd = 0; dd < 4; ++dd) xv[dd] = xn[dd];
  }
  float* ob = out + ((size_t)n << 18) + k0;
#pragma unroll
  for (int c = 0; c < 64; ++c)
    *reinterpret_cast<float2*>(ob + ((size_t)c << 12)) = acc[c];
}

extern "C" void kernel_launch(void* const* d_in, const int* in_sizes, int n_in,
                              void* d_out, int out_size, void* d_ws, size_t ws_size,
                              hipStream_t stream) {
  const float* x = (const float*)d_in[0];
  const float* weight = (const float*)d_in[1];
  const float* bias = (const float*)d_in[2];
  float* out = (float*)d_out;
  char* ws = (char*)d_ws;
  double* S = (double*)ws;
  double* rowsum = (double*)(ws + 32768);
  float* T = (float*)(ws + 33280);
  float* offv = (float*)(ws + 49664);

  hipLaunchKernelGGL(zca_zero_k, dim3(1), dim3(256), 0, stream, S);
  hipLaunchKernelGGL(zca_gram_k, dim3(512), dim3(256), 0, stream, x, S, rowsum);
  hipLaunchKernelGGL(zca_solve_k, dim3(1), dim3(256), 0, stream, S, rowsum, weight, bias, T, offv);
  hipLaunchKernelGGL(zca_apply_k, dim3(512), dim3(256), 0, stream, x, T, offv, out);
}

// Round 4
// 473.194 us; speedup vs baseline: 2.5008x; 1.3177x over previous
//
#include <hip/hip_runtime.h>

// Problem: N=C=H=W=64. n = N*H*W = 262144 samples per channel.
// ws layout:
//   [0,     32768)  S      double[64*64]   Gram accumulator
//   [32768, 33280)  rowsum double[64]
//   [33280, 49664)  T      float[64*64]    folded transform
//   [49664, 49920)  off    float[64]       folded offset

__global__ __launch_bounds__(256) void zca_zero_k(double* __restrict__ p) {
  for (int i = threadIdx.x; i < 4160; i += 256) p[i] = 0.0;
}

// Gram + row sums. Grid 512: (n = b>>3, hw eighth = b&7). 4 tiles of 128.
// Tile staged TRANSPOSED: XT[kk][c] so both operand fragments are b128 reads.
__global__ __launch_bounds__(256) void zca_gram_k(const float* __restrict__ x,
                                                  double* __restrict__ S,
                                                  double* __restrict__ rowsum) {
  __shared__ float XT[128 * 72];  // row kk (stride 72), 64 channels
  const int t = threadIdx.x;
  const int n = blockIdx.x >> 3;
  const int k0base = (blockIdx.x & 7) << 9;
  const float* xb = x + ((size_t)n << 18);
  const int cg = t >> 4, dg = t & 15;
  const int sc = t & 63, kq = t >> 6;

  double acc[4][4];
#pragma unroll
  for (int i = 0; i < 4; ++i)
#pragma unroll
    for (int j = 0; j < 4; ++j) acc[i][j] = 0.0;
  double rs[4] = {0.0, 0.0, 0.0, 0.0};

  for (int tile = 0; tile < 4; ++tile) {
    const int k0 = k0base + (tile << 7);
#pragma unroll
    for (int r = 0; r < 8; ++r) {
      const int kk = ((kq << 3) + r) << 2;
      const float4 v = *reinterpret_cast<const float4*>(xb + ((size_t)sc << 12) + k0 + kk);
      XT[(kk + 0) * 72 + sc] = v.x;
      XT[(kk + 1) * 72 + sc] = v.y;
      XT[(kk + 2) * 72 + sc] = v.z;
      XT[(kk + 3) * 72 + sc] = v.w;
    }
    __syncthreads();
    float accf[4][4];
#pragma unroll
    for (int i = 0; i < 4; ++i)
#pragma unroll
      for (int j = 0; j < 4; ++j) accf[i][j] = 0.0f;
    float rsf[4] = {0.f, 0.f, 0.f, 0.f};
#pragma unroll 2
    for (int kk = 0; kk < 128; ++kk) {
      const float4 a4 = *reinterpret_cast<const float4*>(XT + kk * 72 + (cg << 2));
      const float4 b4 = *reinterpret_cast<const float4*>(XT + kk * 72 + (dg << 2));
      const float a[4] = {a4.x, a4.y, a4.z, a4.w};
      const float b[4] = {b4.x, b4.y, b4.z, b4.w};
#pragma unroll
      for (int i = 0; i < 4; ++i) {
#pragma unroll
        for (int j = 0; j < 4; ++j) accf[i][j] = fmaf(a[i], b[j], accf[i][j]);
        rsf[i] += a[i];
      }
    }
#pragma unroll
    for (int i = 0; i < 4; ++i) {
#pragma unroll
      for (int j = 0; j < 4; ++j) acc[i][j] += (double)accf[i][j];
      rs[i] += (double)rsf[i];
    }
    __syncthreads();
  }
  const int c0 = cg << 2, d0 = dg << 2;
#pragma unroll
  for (int i = 0; i < 4; ++i)
#pragma unroll
    for (int j = 0; j < 4; ++j)
      atomicAdd(&S[(c0 + i) * 64 + d0 + j], acc[i][j]);
  if (dg == 0) {
#pragma unroll
    for (int i = 0; i < 4; ++i) atomicAdd(&rowsum[c0 + i], rs[i]);
  }
}

// round-robin tournament pairing: 32 disjoint pairs covering all 64 indices.
__device__ __forceinline__ void zca_sched(int j, int r, int& p, int& q) {
  if (j == 0) {
    p = 0;
    int a = 62 + r; if (a >= 63) a -= 63;
    q = 1 + a;
  } else {
    int a = j - 1 + r;  if (a >= 63) a -= 63;
    int b = 62 - j + r; if (b >= 63) b -= 63;
    p = 1 + a;
    q = 1 + b;
  }
}

// Single block. One-sided (Hestenes) Jacobi on columns of G = M0, f32,
// run by ONE WAVE (64 lanes, 2 lanes per pair, 32 elems/lane):
//  - no __syncthreads in the sweep loop (wave64 lockstep + in-order DS pipe)
//  - no V matrix: at convergence G = M0*V, so v_i = G[:,i]/||G[:,i]||
//  - incremental norms: app' = app - t*apq, aqq' = aqq + t*apq
//  - relative skip threshold + __any()-ballot early exit
__global__ __launch_bounds__(256) void zca_solve_k(const double* __restrict__ S,
                                                   const double* __restrict__ rowsum,
                                                   const float* __restrict__ weight,
                                                   const float* __restrict__ bias,
                                                   float* __restrict__ T,
                                                   float* __restrict__ offv) {
  __shared__ __align__(16) float G[64 * 68];  // column-major, col stride 68
  __shared__ float norms[64];                 // running squared col norms
  __shared__ float lam[64];
  __shared__ float msd[64];                   // mu/sig (f32)
  __shared__ float isg[64];                   // 1/sig (f32)
  __shared__ double mu[64], sig[64];
  __shared__ float wk2[64];                   // active * lam^(-5/2)
  __shared__ int idxs[64];
  const int t = threadIdx.x;
  const double n = 262144.0;

  if (t < 64) {
    const double m = rowsum[t] / n;
    const double var = (S[t * 64 + t] - n * m * m) / (n - 1.0);
    mu[t] = m;
    sig[t] = sqrt(var + 1e-5);
    msd[t] = (float)(m / sig[t]);
    isg[t] = (float)(1.0 / sig[t]);
  }
  __syncthreads();
  for (int e = t; e < 4096; e += 256) {
    const int col = e >> 6, row = e & 63;
    double v = (S[row * 64 + col] - n * mu[row] * mu[col]) / (n * sig[row] * sig[col]);
    if (row == col) v += 1e-5;
    G[col * 68 + row] = (float)v;
  }
  __syncthreads();
  if (t < 64) {  // initial squared column norms (= (M0^2)_tt)
    float s = 0.0f;
#pragma unroll
    for (int j4 = 0; j4 < 16; ++j4) {
      const float4 v = *reinterpret_cast<const float4*>(G + t * 68 + (j4 << 2));
      s = fmaf(v.x, v.x, s); s = fmaf(v.y, v.y, s);
      s = fmaf(v.z, v.z, s); s = fmaf(v.w, v.w, s);
    }
    norms[t] = s;
  }
  __syncthreads();

  if (t < 64) {  // ---- single-wave Jacobi sweep loop, zero barriers ----
    const int g = t >> 1;
    const int o = (t & 1) << 5;  // 32 elements per lane
    for (int sweep = 0; sweep < 8; ++sweep) {
      int anyflag = 0;
      for (int round = 0; round < 63; ++round) {
        int p, q;
        zca_sched(g, round, p, q);
        float* Gp = G + p * 68 + o;
        float* Gq = G + q * 68 + o;
        float4 P[8], Q[8];
#pragma unroll
        for (int i = 0; i < 8; ++i) P[i] = *reinterpret_cast<float4*>(Gp + (i << 2));
#pragma unroll
        for (int i = 0; i < 8; ++i) Q[i] = *reinterpret_cast<float4*>(Gq + (i << 2));
        float apq = 0.0f;
#pragma unroll
        for (int i = 0; i < 8; ++i) {
          apq = fmaf(P[i].x, Q[i].x, apq);
          apq = fmaf(P[i].y, Q[i].y, apq);
          apq = fmaf(P[i].z, Q[i].z, apq);
          apq = fmaf(P[i].w, Q[i].w, apq);
        }
        apq += __shfl_xor(apq, 1);
        const float app = norms[p], aqq = norms[q];
        if (apq * apq > 1e-11f * app * aqq) {
          anyflag = 1;
          const float tau = (aqq - app) / (2.0f * apq);
          const float tt = (tau >= 0.0f ? 1.0f : -1.0f) / (fabsf(tau) + sqrtf(1.0f + tau * tau));
          const float c = 1.0f / sqrtf(1.0f + tt * tt);
          const float s = tt * c;
#pragma unroll
          for (int i = 0; i < 8; ++i) {
            float4 np, nq;
            np.x = c * P[i].x - s * Q[i].x; np.y = c * P[i].y - s * Q[i].y;
            np.z = c * P[i].z - s * Q[i].z; np.w = c * P[i].w - s * Q[i].w;
            nq.x = s * P[i].x + c * Q[i].x; nq.y = s * P[i].y + c * Q[i].y;
            nq.z = s * P[i].z + c * Q[i].z; nq.w = s * P[i].w + c * Q[i].w;
            *reinterpret_cast<float4*>(Gp + (i << 2)) = np;
            *reinterpret_cast<float4*>(Gq + (i << 2)) = nq;
          }
          if ((t & 1) == 0) norms[p] = app - tt * apq;
          else              norms[q] = aqq + tt * apq;
        }
        __builtin_amdgcn_wave_barrier();  // pin LDS program order across rounds
      }
      if (!__any(anyflag)) break;
    }
  }
  __syncthreads();

  // eigenvalues = exact column norms of converged G (G[:,i] = lam_i * v_i)
  if (t < 64) {
    float s = 0.0f;
#pragma unroll
    for (int j4 = 0; j4 < 16; ++j4) {
      const float4 v = *reinterpret_cast<const float4*>(G + t * 68 + (j4 << 2));
      s = fmaf(v.x, v.x, s); s = fmaf(v.y, v.y, s);
      s = fmaf(v.z, v.z, s); s = fmaf(v.w, v.w, s);
    }
    lam[t] = sqrtf(s);
  }
  __syncthreads();
  if (t < 64) {
    const float e = lam[t];
    int rank = 0;
    for (int j = 0; j < 64; ++j) {
      const float ej = lam[j];
      if (ej > e || (ej == e && j < t)) ++rank;
    }
    idxs[rank] = t;
  }
  __syncthreads();
  if (t == 0) {
    double total = 0.0;
    for (int j = 0; j < 64; ++j) total += (double)lam[j];
    double cum = 0.0;
    bool done = false;
    for (int k = 0; k < 64; ++k) {
      const double l = (double)lam[idxs[k]];
      cum += l;
      double w = 0.0;
      if (k < 32 && !done) w = 1.0 / (sqrt(l) * l * l);  // lam^(-1/2) / lam^2
      if (cum / total >= 0.95) done = true;
      wk2[k] = (float)w;
    }
  }
  __syncthreads();
  // Wxr[c][d] = sum_k wk2[k] * G[c,idx_k] * G[d,idx_k]; fold into T and off.
  {
    const int c = t >> 2, db = (t & 3) << 4;
    float accf[16];
#pragma unroll
    for (int d = 0; d < 16; ++d) accf[d] = 0.0f;
    for (int k = 0; k < 32; ++k) {
      const int sk = idxs[k];
      const float vc = wk2[k] * G[sk * 68 + c];
      const float* gcol = G + sk * 68 + db;
#pragma unroll
      for (int d4 = 0; d4 < 4; ++d4) {
        const float4 v = *reinterpret_cast<const float4*>(gcol + (d4 << 2));
        accf[d4 * 4 + 0] = fmaf(vc, v.x, accf[d4 * 4 + 0]);
        accf[d4 * 4 + 1] = fmaf(vc, v.y, accf[d4 * 4 + 1]);
        accf[d4 * 4 + 2] = fmaf(vc, v.z, accf[d4 * 4 + 2]);
        accf[d4 * 4 + 3] = fmaf(vc, v.w, accf[d4 * 4 + 3]);
      }
    }
    const float wc = weight[c];
    float po = 0.0f;
#pragma unroll
    for (int d = 0; d < 16; ++d) {
      T[c * 64 + db + d] = wc * accf[d] * isg[db + d];
      po = fmaf(accf[d], msd[db + d], po);
    }
    po += __shfl_xor(po, 1);
    po += __shfl_xor(po, 2);
    if ((t & 3) == 0) offv[c] = bias[c] - wc * po;
  }
}

// out[n,c,k] = sum_d T[c][d]*x[n,d,k] + off[c].
// Grid 512: (n = b>>3, 512 k per block, 2 positions per thread).
__global__ __launch_bounds__(256) void zca_apply_k(const float* __restrict__ x,
                                                   const float* __restrict__ T,
                                                   const float* __restrict__ offv,
                                                   float* __restrict__ out) {
  __shared__ __align__(16) float4 Tl4[64 * 16];  // Tl4[c*16 + d4]
  __shared__ float offl[64];
  const int t = threadIdx.x;
  for (int e = t; e < 1024; e += 256) Tl4[e] = reinterpret_cast<const float4*>(T)[e];
  if (t < 64) offl[t] = offv[t];
  __syncthreads();
  const int n = blockIdx.x >> 3;
  const int k0 = ((blockIdx.x & 7) << 9) + (t << 1);
  const float* xb = x + ((size_t)n << 18) + k0;
  float2 acc[64];
#pragma unroll
  for (int c = 0; c < 64; ++c) { acc[c].x = offl[c]; acc[c].y = offl[c]; }
  float2 xv[4];
#pragma unroll
  for (int dd = 0; dd < 4; ++dd)
    xv[dd] = *reinterpret_cast<const float2*>(xb + ((size_t)dd << 12));
  for (int d4 = 0; d4 < 16; ++d4) {
    float2 xn[4];
    if (d4 < 15) {
#pragma unroll
      for (int dd = 0; dd < 4; ++dd)
        xn[dd] = *reinterpret_cast<const float2*>(xb + ((size_t)((d4 + 1) * 4 + dd) << 12));
    }
#pragma unroll
    for (int c = 0; c < 64; ++c) {
      const float4 tv = Tl4[(c << 4) + d4];
      acc[c].x = fmaf(tv.x, xv[0].x, acc[c].x); acc[c].y = fmaf(tv.x, xv[0].y, acc[c].y);
      acc[c].x = fmaf(tv.y, xv[1].x, acc[c].x); acc[c].y = fmaf(tv.y, xv[1].y, acc[c].y);
      acc[c].x = fmaf(tv.z, xv[2].x, acc[c].x); acc[c].y = fmaf(tv.z, xv[2].y, acc[c].y);
      acc[c].x = fmaf(tv.w, xv[3].x, acc[c].x); acc[c].y = fmaf(tv.w, xv[3].y, acc[c].y);
    }
#pragma unroll
    for (int dd = 0; dd < 4; ++dd) xv[dd] = xn[dd];
  }
  float* ob = out + ((size_t)n << 18) + k0;
#pragma unroll
  for (int c = 0; c < 64; ++c)
    *reinterpret_cast<float2*>(ob + ((size_t)c << 12)) = acc[c];
}

extern "C" void kernel_launch(void* const* d_in, const int* in_sizes, int n_in,
                              void* d_out, int out_size, void* d_ws, size_t ws_size,
                              hipStream_t stream) {
  const float* x = (const float*)d_in[0];
  const float* weight = (const float*)d_in[1];
  const float* bias = (const float*)d_in[2];
  float* out = (float*)d_out;
  char* ws = (char*)d_ws;
  double* S = (double*)ws;
  double* rowsum = (double*)(ws + 32768);
  float* T = (float*)(ws + 33280);
  float* offv = (float*)(ws + 49664);

  hipLaunchKernelGGL(zca_zero_k, dim3(1), dim3(256), 0, stream, S);
  hipLaunchKernelGGL(zca_gram_k, dim3(512), dim3(256), 0, stream, x, S, rowsum);
  hipLaunchKernelGGL(zca_solve_k, dim3(1), dim3(256), 0, stream, S, rowsum, weight, bias, T, offv);
  hipLaunchKernelGGL(zca_apply_k, dim3(512), dim3(256), 0, stream, x, T, offv, out);
}